// Round 3
// baseline (349.497 us; speedup 1.0000x reference)
//
#include <hip/hip_runtime.h>
#include <hip/hip_bf16.h>
#include <math.h>

// Problem constants (B=4, S=2048, D=768, H=3072, E=8, K=2, cap_factor=1.5)
#define TOK    8192          // B*S tokens
#define DMODEL 768
#define HDIM   3072
#define NEXP   8
#define CAP    1536          // int((B*S/E)*1.5)
#define NFLAT  (TOK*2)

typedef __attribute__((ext_vector_type(8))) short bf16x8;
typedef __attribute__((ext_vector_type(4))) float f32x4;

static __device__ __forceinline__ unsigned short f2bf(float f) {
  unsigned int u = __float_as_uint(f);
  u += 0x7FFF + ((u >> 16) & 1);          // round-to-nearest-even
  return (unsigned short)(u >> 16);
}

static __device__ __forceinline__ void gld_lds16(const void* g, void* l) {
  __builtin_amdgcn_global_load_lds((const __attribute__((address_space(1))) void*)g,
                                   (__attribute__((address_space(3))) void*)l,
                                   16, 0, 0);
}

#define SBAR() __builtin_amdgcn_s_barrier()
#define LGKM0() do { asm volatile("s_waitcnt lgkmcnt(0)" ::: "memory"); \
                     __builtin_amdgcn_sched_barrier(0); } while (0)

// ---------------- 1. Router: fp64 logits, top-2, renormalized weights ----------------
__global__ __launch_bounds__(256)
void moe_router(const float* __restrict__ x, const float* __restrict__ Wr,
                int* __restrict__ eidx, float* __restrict__ pw)
{
  const int wid = threadIdx.x >> 6, lane = threadIdx.x & 63;
  const int t = blockIdx.x * 4 + wid;
  const float* xr = x + (size_t)t * DMODEL;
  double acc[NEXP];
#pragma unroll
  for (int e = 0; e < NEXP; ++e) acc[e] = 0.0;
  for (int j = 0; j < DMODEL / 64; ++j) {
    const int d = j * 64 + lane;
    const double xv = (double)xr[d];
    const float* wrow = Wr + (size_t)d * NEXP;
#pragma unroll
    for (int e = 0; e < NEXP; ++e) acc[e] += xv * (double)wrow[e];
  }
#pragma unroll
  for (int off = 32; off > 0; off >>= 1) {
#pragma unroll
    for (int e = 0; e < NEXP; ++e) acc[e] += __shfl_xor(acc[e], off, 64);
  }
  if (lane == 0) {
    int e0 = 0;
    for (int e = 1; e < NEXP; ++e) if (acc[e] > acc[e0]) e0 = e;
    int e1 = (e0 == 0) ? 1 : 0;
    for (int e = 0; e < NEXP; ++e) { if (e == e0) continue; if (acc[e] > acc[e1]) e1 = e; }
    const double p0 = 1.0 / (1.0 + exp(acc[e1] - acc[e0]));
    eidx[t * 2 + 0] = e0; eidx[t * 2 + 1] = e1;
    pw[t * 2 + 0] = (float)p0; pw[t * 2 + 1] = (float)(1.0 - p0);
  }
}

// ---------------- 2. Capacity assignment ----------------
__global__ __launch_bounds__(256)
void moe_assign(const int* __restrict__ eidx, int* __restrict__ slotpos,
                int* __restrict__ elist, int* __restrict__ counts)
{
  const int e = blockIdx.x;
  const int tid = threadIdx.x;
  const int base = tid * 64;
  int cnt = 0;
  for (int j = 0; j < 64; ++j) cnt += (eidx[base + j] == e);
  const int lane = tid & 63, wid = tid >> 6;
  int incl = cnt;
  for (int off = 1; off < 64; off <<= 1) {
    int u = __shfl_up(incl, off, 64);
    if (lane >= off) incl += u;
  }
  __shared__ int wsum[4];
  if (lane == 63) wsum[wid] = incl;
  __syncthreads();
  int wbase = 0;
  for (int w = 0; w < wid; ++w) wbase += wsum[w];
  int run = wbase + incl - cnt;
  for (int j = 0; j < 64; ++j) {
    const int n = base + j;
    if (eidx[n] == e) {
      const int pos = run++;
      slotpos[n] = (pos < CAP) ? pos : -1;
      if (pos < CAP) elist[e * CAP + pos] = n >> 1;
    }
  }
  if (tid == 255) {
    int tot = wbase + incl;
    counts[e] = (tot < CAP) ? tot : CAP;
  }
}

// ---------------- 3. Transpose + fp32->bf16 convert (weights) ----------------
__global__ __launch_bounds__(256)
void transpose_bf16(const float* __restrict__ in, unsigned short* __restrict__ out,
                    int R, int C)
{
  __shared__ unsigned short tile[64][65];
  const int e = blockIdx.z;
  in  += (size_t)e * R * C;
  out += (size_t)e * C * R;
  const int c0 = blockIdx.x * 64;
  const int r0 = blockIdx.y * 64;
  const int tid = threadIdx.x;
#pragma unroll
  for (int i = 0; i < 16; ++i) {
    const int L = tid + i * 256;
    const int r = L >> 6, c = L & 63;
    tile[r][c] = f2bf(in[(size_t)(r0 + r) * C + c0 + c]);
  }
  __syncthreads();
#pragma unroll
  for (int i = 0; i < 16; ++i) {
    const int L = tid + i * 256;
    const int rr = L & 63, cc = L >> 6;
    out[(size_t)(c0 + cc) * R + r0 + rr] = tile[rr][cc];
  }
}

// ---------------- 4. Gather tokens per expert into contiguous bf16 rows ----------------
__global__ __launch_bounds__(64)
void moe_gather(const float* __restrict__ x, const int* __restrict__ elist,
                const int* __restrict__ counts, unsigned short* __restrict__ Xg)
{
  const int p = blockIdx.x, e = blockIdx.y;
  const int lane = threadIdx.x;
  unsigned short* dst = Xg + ((size_t)e * CAP + p) * DMODEL;
  if (p >= counts[e]) {
    ushort4 z; z.x = z.y = z.z = z.w = 0;
#pragma unroll
    for (int j = 0; j < 3; ++j) ((ushort4*)dst)[j * 64 + lane] = z;
    return;
  }
  const int tok = elist[e * CAP + p];
  const float4* src = (const float4*)(x + (size_t)tok * DMODEL);
#pragma unroll
  for (int j = 0; j < 3; ++j) {
    float4 v = src[j * 64 + lane];
    ushort4 o;
    o.x = f2bf(v.x); o.y = f2bf(v.y); o.z = f2bf(v.z); o.w = f2bf(v.w);
    ((ushort4*)dst)[j * 64 + lane] = o;
  }
}

// ---------------- 5. Grouped GEMM, 8-phase 256x256, fragment-linear LDS ----------------
// C[m,n] = A[m,:] . B[n,:] (both k-major). 512 threads = 8 waves (2 M x 4 N).
// LDS holds MFMA fragment-blocks contiguously (1024B per 16-row x 32-k block),
// staged by global_load_lds with PRE-PERMUTED global source addresses so the
// linear lane-order LDS write lands exactly in ds_read fragment order; every
// ds_read_b128 then reads 1024 consecutive bytes (conflict-free, mirrors the
// write pattern). Per-phase end-of-phase vmcnt(12): every staged half has
// exactly 12 VMEM instrs issued after it at its read deadline => each load
// gets a 6-phase (~1200 cyc) landing window. Tail (t>=NT-3): vmcnt(0).
// EPI=0: C=bf16(gelu(acc+bias));  EPI=1: C=f32(acc+bias).
template <int EPI>
__global__ __launch_bounds__(512)
void moe_gemm8(const unsigned short* __restrict__ Ag, int lda,
               const unsigned short* __restrict__ Bg, int ldb,
               void* __restrict__ Cout, int ldc,
               const float* __restrict__ bias,
               int Nsize, int NT, int MT, int NTN)
{
  // A: 4 buffers (2 tiles x 2 k-halves) x 16KB; B same. 128 KiB total.
  __shared__ __align__(16) unsigned short lds[4 * 8192 + 4 * 8192];

  // block decode with XCD-bijective swizzle (gridDim.x % 8 == 0).
  // per_e = MT*NTN is a multiple of grid/8 divisor layout: each XCD gets a
  // contiguous run of tiles; consecutive swz share the same B panel (mt fastest).
  const int nwg = gridDim.x;
  const int cpx = nwg >> 3;
  const int swz = (blockIdx.x & 7) * cpx + (blockIdx.x >> 3);
  const int per_e = MT * NTN;
  const int e = swz / per_e;
  const int rdec = swz - e * per_e;
  const int mt = rdec % MT;
  const int nt = rdec / MT;
  const int m0 = mt * 256, n0 = nt * 256;

  const unsigned short* Ae = Ag + (size_t)e * CAP * lda;
  const unsigned short* Be = Bg + (size_t)e * Nsize * ldb;

  const int tid  = threadIdx.x;
  const int lane = tid & 63, wid = tid >> 6;
  const int wr = wid >> 2, wc = wid & 3;    // 2x4 wave grid; per-wave 128x64 out
  const int r16 = lane & 15, g4 = lane >> 4;

  // staging source: thread tid covers fragment-block (c*8 + wid), lane (tid&63):
  //   global row = (c*8+wid)*16 + (tid&15), k-chunk = (tid>>4)&3  (==g4)
  const unsigned short* aSrc = Ae + (size_t)(m0 + ((tid >> 6) << 4) + (tid & 15)) * lda + g4 * 8;
  const unsigned short* bSrc = Be + (size_t)(n0 + ((tid >> 6) << 4) + (tid & 15)) * ldb + g4 * 8;

  auto stageA = [&](int tt, int kh) {
    const int b = tt & 1;
    unsigned short* s = &lds[(b * 2 + kh) * 8192 + wid * 512];
    const unsigned short* gp = aSrc + tt * 64 + kh * 32;
    gld_lds16(gp,                    s);
    gld_lds16(gp + (size_t)128 * lda, s + 4096);
  };
  auto stageB = [&](int tt, int kh) {
    const int b = tt & 1;
    unsigned short* s = &lds[32768 + (b * 2 + kh) * 8192 + wid * 512];
    const unsigned short* gp = bSrc + tt * 64 + kh * 32;
    gld_lds16(gp,                    s);
    gld_lds16(gp + (size_t)128 * ldb, s + 4096);
  };
  // reads: fragment-block fb = row>>4 (A) or col>>4 (B); 1024B linear per wave
  auto loadA = [&](int b, int kh, int mi) -> bf16x8 {
    return *(const bf16x8*)&lds[(b * 2 + kh) * 8192 + (wr * 8 + mi) * 512 + lane * 8];
  };
  auto loadB = [&](int b, int kh, int ni) -> bf16x8 {
    return *(const bf16x8*)&lds[32768 + (b * 2 + kh) * 8192 + (wc * 4 + ni) * 512 + lane * 8];
  };

  f32x4 acc[8][4];
#pragma unroll
  for (int i = 0; i < 8; ++i)
#pragma unroll
    for (int j = 0; j < 4; ++j) acc[i][j] = (f32x4){0.f, 0.f, 0.f, 0.f};

  bf16x8 aA0[8], aA1[8], bB0[4], bB1[4];

  // prologue: B0(0) A0(0) B1(0) A1(0) B0(1) A0(1) B1(1) -- 14 VMEM instrs
  stageB(0, 0); stageA(0, 0); stageB(0, 1); stageA(0, 1);
  stageB(1, 0); stageA(1, 0); stageB(1, 1);
  asm volatile("s_waitcnt vmcnt(12)" ::: "memory");   // B0(0) landed
  SBAR();

#define WAITV() do { if (t < NT - 3) asm volatile("s_waitcnt vmcnt(12)" ::: "memory"); \
                     else            asm volatile("s_waitcnt vmcnt(0)"  ::: "memory"); } while (0)

  for (int t = 0; t < NT; ++t) {
    const int b = t & 1;
    // ---- phase 1: read B-kk0(t); stage A-kk1(t+1); MFMA leftover kk1 x n-hi (t-1)
#pragma unroll
    for (int ni = 0; ni < 4; ++ni) bB0[ni] = loadB(b, 0, ni);
    if (t + 1 < NT) stageA(t + 1, 1);
    SBAR(); LGKM0();
    __builtin_amdgcn_s_setprio(1);
    if (t > 0) {
#pragma unroll
      for (int mi = 0; mi < 8; ++mi)
#pragma unroll
        for (int q = 0; q < 2; ++q)
          acc[mi][2 + q] = __builtin_amdgcn_mfma_f32_16x16x32_bf16(
              aA1[mi], bB1[2 + q], acc[mi][2 + q], 0, 0, 0);
    }
    __builtin_amdgcn_s_setprio(0);
    WAITV();   // covers A-kk0(t) for phase 2
    SBAR();
    // ---- phase 2: read A-kk0(t); stage B-kk0(t+2); MFMA kk0 x n-lo
#pragma unroll
    for (int mi = 0; mi < 8; ++mi) aA0[mi] = loadA(b, 0, mi);
    if (t + 2 < NT) stageB(t + 2, 0);
    SBAR(); LGKM0();
    __builtin_amdgcn_s_setprio(1);
#pragma unroll
    for (int mi = 0; mi < 8; ++mi)
#pragma unroll
      for (int q = 0; q < 2; ++q)
        acc[mi][q] = __builtin_amdgcn_mfma_f32_16x16x32_bf16(
            aA0[mi], bB0[q], acc[mi][q], 0, 0, 0);
    __builtin_amdgcn_s_setprio(0);
    WAITV();   // covers B-kk1(t) for phase 3
    SBAR();
    // ---- phase 3: read B-kk1(t); stage A-kk0(t+2); MFMA kk0 x n-hi
#pragma unroll
    for (int ni = 0; ni < 4; ++ni) bB1[ni] = loadB(b, 1, ni);
    if (t + 2 < NT) stageA(t + 2, 0);
    SBAR(); LGKM0();
    __builtin_amdgcn_s_setprio(1);
#pragma unroll
    for (int mi = 0; mi < 8; ++mi)
#pragma unroll
      for (int q = 0; q < 2; ++q)
        acc[mi][2 + q] = __builtin_amdgcn_mfma_f32_16x16x32_bf16(
            aA0[mi], bB0[2 + q], acc[mi][2 + q], 0, 0, 0);
    __builtin_amdgcn_s_setprio(0);
    WAITV();   // covers A-kk1(t) for phase 4
    SBAR();
    // ---- phase 4: read A-kk1(t); stage B-kk1(t+2); MFMA kk1 x n-lo
#pragma unroll
    for (int mi = 0; mi < 8; ++mi) aA1[mi] = loadA(b, 1, mi);
    if (t + 2 < NT) stageB(t + 2, 1);
    SBAR(); LGKM0();
    __builtin_amdgcn_s_setprio(1);
#pragma unroll
    for (int mi = 0; mi < 8; ++mi)
#pragma unroll
      for (int q = 0; q < 2; ++q)
        acc[mi][q] = __builtin_amdgcn_mfma_f32_16x16x32_bf16(
            aA1[mi], bB1[q], acc[mi][q], 0, 0, 0);
    __builtin_amdgcn_s_setprio(0);
    WAITV();   // covers B-kk0(t+1) for phase 1 of next tile
    SBAR();
  }
#undef WAITV
  // leftover: kk1 x n-hi of the last tile (registers still live)
#pragma unroll
  for (int mi = 0; mi < 8; ++mi)
#pragma unroll
    for (int q = 0; q < 2; ++q)
      acc[mi][2 + q] = __builtin_amdgcn_mfma_f32_16x16x32_bf16(
          aA1[mi], bB1[2 + q], acc[mi][2 + q], 0, 0, 0);

  // ---- epilogue. C/D layout: col = lane&15, row = 4*(lane>>4)+reg ----
  const float* bvec = bias + (size_t)e * Nsize;
#pragma unroll
  for (int nr = 0; nr < 4; ++nr) {
    const int gc = n0 + wc * 64 + nr * 16 + r16;
    const float bv = bvec[gc];
#pragma unroll
    for (int mi = 0; mi < 8; ++mi) {
      const int gr0 = m0 + wr * 128 + mi * 16 + 4 * g4;
#pragma unroll
      for (int reg = 0; reg < 4; ++reg) {
        float v = acc[mi][nr][reg] + bv;
        if constexpr (EPI == 0) {
          v = 0.5f * v * (1.0f + erff(v * 0.70710678118654752f));
          ((unsigned short*)Cout)[(size_t)e * CAP * ldc + (size_t)(gr0 + reg) * ldc + gc] = f2bf(v);
        } else {
          ((float*)Cout)[(size_t)e * CAP * ldc + (size_t)(gr0 + reg) * ldc + gc] = v;
        }
      }
    }
  }
}

// ---------------- 6. Combine: out[t] = sum over kept slots w * Y[e][pos] ----------------
__global__ __launch_bounds__(192)
void moe_combine(const float* __restrict__ Y, const int* __restrict__ eidx,
                 const float* __restrict__ pw, const int* __restrict__ slotpos,
                 float* __restrict__ out)
{
  const int t = blockIdx.x;
  const int tid = threadIdx.x;
  float4 acc; acc.x = acc.y = acc.z = acc.w = 0.f;
#pragma unroll
  for (int s = 0; s < 2; ++s) {
    const int pos = slotpos[t * 2 + s];
    if (pos >= 0) {
      const int e = eidx[t * 2 + s];
      const float w = pw[t * 2 + s];
      float4 y = ((const float4*)(Y + ((size_t)e * CAP + pos) * DMODEL))[tid];
      acc.x += w * y.x; acc.y += w * y.y; acc.z += w * y.z; acc.w += w * y.w;
    }
  }
  ((float4*)out)[(size_t)t * (DMODEL / 4) + tid] = acc;
}

// ---------------- launch ----------------
extern "C" void kernel_launch(void* const* d_in, const int* in_sizes, int n_in,
                              void* d_out, int out_size, void* d_ws, size_t ws_size,
                              hipStream_t stream)
{
  const float* x  = (const float*)d_in[0];
  const float* Wr = (const float*)d_in[1];
  const float* w1 = (const float*)d_in[2];
  const float* b1 = (const float*)d_in[3];
  const float* w2 = (const float*)d_in[4];
  const float* b2 = (const float*)d_in[5];
  float* out = (float*)d_out;

  char* ws = (char*)d_ws;
  const size_t SZ_W1T = (size_t)NEXP * HDIM * DMODEL * 2;
  const size_t SZ_W2T = (size_t)NEXP * DMODEL * HDIM * 2;
  const size_t SZ_XG  = (size_t)NEXP * CAP * DMODEL * 2;
  const size_t SZ_H   = (size_t)NEXP * CAP * HDIM * 2;
  const size_t SZ_Y   = (size_t)NEXP * CAP * DMODEL * 4;
  unsigned short* w1t = (unsigned short*)(ws);               size_t off = SZ_W1T;
  unsigned short* w2t = (unsigned short*)(ws + off);         off += SZ_W2T;
  unsigned short* Xg  = (unsigned short*)(ws + off);         off += SZ_XG;
  unsigned short* Hb  = (unsigned short*)(ws + off);         off += SZ_H;
  float*          Yb  = (float*)(ws + off);                  off += SZ_Y;
  int*   eidx    = (int*)(ws + off);                         off += (size_t)TOK * 2 * 4;
  float* pw      = (float*)(ws + off);                       off += (size_t)TOK * 2 * 4;
  int*   slotpos = (int*)(ws + off);                         off += (size_t)NFLAT * 4;
  int*   elist   = (int*)(ws + off);                         off += (size_t)NEXP * CAP * 4;
  int*   counts  = (int*)(ws + off);

  // 1. router (fp64 logits -> exact top-2 ordering)
  moe_router<<<TOK / 4, 256, 0, stream>>>(x, Wr, eidx, pw);
  // 2. capacity assignment
  moe_assign<<<NEXP, 256, 0, stream>>>(eidx, slotpos, elist, counts);
  // 3. weight transposes (n-major bf16)
  transpose_bf16<<<dim3(HDIM / 64, DMODEL / 64, NEXP), 256, 0, stream>>>(w1, w1t, DMODEL, HDIM);
  transpose_bf16<<<dim3(DMODEL / 64, HDIM / 64, NEXP), 256, 0, stream>>>(w2, w2t, HDIM, DMODEL);
  // 4. gather per-expert token rows (bf16), zero pad rows
  moe_gather<<<dim3(CAP, NEXP), 64, 0, stream>>>(x, elist, counts, Xg);
  // 5. grouped GEMMs (8-phase, fragment-linear LDS)
  //    GEMM1: [1536x3072x768]/expert, 256x256 -> 8*6*12 = 576 blocks, NT=12
  moe_gemm8<0><<<576, 512, 0, stream>>>(
      Xg, DMODEL, w1t, DMODEL, Hb, HDIM, b1, HDIM, /*NT=*/12, /*MT=*/6, /*NTN=*/12);
  //    GEMM2: [1536x768x3072]/expert, 256x256 -> 8*6*3 = 144 blocks (1 expert/XCD), NT=48
  moe_gemm8<1><<<144, 512, 0, stream>>>(
      Hb, HDIM, w2t, HDIM, Yb, DMODEL, b2, DMODEL, /*NT=*/48, /*MT=*/6, /*NTN=*/3);
  // 6. weighted combine (deterministic, no atomics)
  moe_combine<<<TOK, 192, 0, stream>>>(Yb, eidx, pw, slotpos, out);
}